// Round 1
// 889.042 us; speedup vs baseline: 1.2559x; 1.2559x over previous
//
#include <hip/hip_runtime.h>

// Problem constants
#define T_STEPS 256
#define B_SZ    4096
#define I_SZ    144
#define H_SZ    32
#define W_LD    176   // H + I

// photonic sigmoid constants
#define PS_A1   0.06f
#define PS_A2   1.005f
#define PS_X0   0.145f
#define PS_D    0.033f
#define PS_CUT  2.0f

typedef const __attribute__((address_space(1))) float* gas_fp;
typedef __attribute__((address_space(3))) float* las_fp;

__device__ __forceinline__ void dma16(const float* g, float* l) {
    // 16B per active lane, LDS dest = wave-uniform base + lane*16
    __builtin_amdgcn_global_load_lds((gas_fp)g, (las_fp)l, 16, 0, 0);
}

__device__ __forceinline__ float psig(float z) {
    const float expC = (float)(1.0 / (0.033 * 0.6931471805599453)); // 1/(D*ln2)
    float zz = fminf(z - PS_X0, PS_CUT);
    float e  = exp2f(zz * expC);
#if __has_builtin(__builtin_amdgcn_rcpf)
    float r = __builtin_amdgcn_rcpf(1.0f + e);
#else
    float r = 1.0f / (1.0f + e);
#endif
    return fmaf(PS_A1 - PS_A2, r, PS_A2);
}

// -----------------------------------------------------------------------------
// Fused kernel: 1 wave = 1 batch chain, all 256 steps, no inter-block sync.
// lane = (q, j): q = k-quarter (44 wide), j in [0,16); lane computes partial
// dots for outputs j and j+16 over its k-quarter. W slices live in 88 VGPRs.
// v_t = [h(32) | x_t(144)] contiguous in a 4-deep LDS ring; x_t DMA'd 2 steps
// ahead via global_load_lds; counted vmcnt(2) keeps the pipe deep.
// -----------------------------------------------------------------------------
__global__ __launch_bounds__(64, 4) void fused_rnn(
    const float* __restrict__ x,     // [256][4096][144]
    const float* __restrict__ W,     // [32][176]  (Wh = cols 0..31, Wx = 32..175)
    const float* __restrict__ bias,  // [32]
    float* __restrict__ out)         // [4096][32]
{
    const int tid = threadIdx.x;
    const int j   = tid & 15;
    const int q   = tid >> 4;
    const int b   = blockIdx.x;

    __shared__ float vbuf[4][256];   // [ring][ h(32) | x(144) | pad ]

    // ---- one-time: W slices -> registers (t-invariant) ----
    float wA[44], wB[44];
    {
        const float* wa = W + j * W_LD + q * 44;
        const float* wb = W + (j + 16) * W_LD + q * 44;
#pragma unroll
        for (int i = 0; i < 11; ++i) {
            float4 va = *(const float4*)(wa + 4 * i);
            float4 vc = *(const float4*)(wb + 4 * i);
            wA[4*i+0] = va.x; wA[4*i+1] = va.y; wA[4*i+2] = va.z; wA[4*i+3] = va.w;
            wB[4*i+0] = vc.x; wB[4*i+1] = vc.y; wB[4*i+2] = vc.z; wB[4*i+3] = vc.w;
        }
    }
    const float biasA = bias[j];
    const float biasB = bias[j + 16];

    // drain one-time loads so the loop's vmcnt bookkeeping counts only DMAs
    asm volatile("s_waitcnt vmcnt(0)" ::: "memory");

    // h0 state = 0 in ring slot 0
    if (q == 0) { vbuf[0][j] = 0.0f; vbuf[0][16 + j] = 0.0f; }

    const size_t tstride = (size_t)B_SZ * I_SZ;          // floats per t-slab
    const float* xrow = x + (size_t)b * I_SZ + tid * 4;  // lane's 16B slot
    const bool ld = (tid < 36);                          // 36*16B = 576B row

    if (ld) {
        dma16(xrow,           &vbuf[0][H_SZ]);           // x[0]
        dma16(xrow + tstride, &vbuf[1][H_SZ]);           // x[1]
    }
    const float* xsrc = xrow + 2 * tstride;              // next DMA source: x[t+2]

    float h0 = 0.0f, h1 = 0.0f;

    for (int t = 0; t < T_STEPS; ++t) {
        // issue prefetch for t+2 (clamped dups at the tail keep counts uniform)
        if (ld) dma16(xsrc, &vbuf[(t + 2) & 3][H_SZ]);
        if (t < T_STEPS - 3) xsrc += tstride;

        // wait for x[t] only; keep 2 DMAs in flight across the iteration
        asm volatile("s_waitcnt vmcnt(2)" ::: "memory");
        __builtin_amdgcn_sched_barrier(0);

        const float* vb = &vbuf[t & 3][q * 44];
        float a0=0.f, a1=0.f, a2=0.f, a3=0.f;
        float c0=0.f, c1=0.f, c2=0.f, c3=0.f;
#pragma unroll
        for (int i = 0; i < 11; ++i) {
            float4 v = *(const float4*)(vb + 4 * i);     // broadcast ds_read_b128
            a0 = fmaf(wA[4*i+0], v.x, a0);
            a1 = fmaf(wA[4*i+1], v.y, a1);
            a2 = fmaf(wA[4*i+2], v.z, a2);
            a3 = fmaf(wA[4*i+3], v.w, a3);
            c0 = fmaf(wB[4*i+0], v.x, c0);
            c1 = fmaf(wB[4*i+1], v.y, c1);
            c2 = fmaf(wB[4*i+2], v.z, c2);
            c3 = fmaf(wB[4*i+3], v.w, c3);
        }
        float pA = (a0 + a1) + (a2 + a3);
        float pB = (c0 + c1) + (c2 + c3);
        // butterfly over the 4 k-quarters (lanes j, 16+j, 32+j, 48+j)
        pA += __shfl_xor(pA, 16, 64);
        pA += __shfl_xor(pA, 32, 64);
        pB += __shfl_xor(pB, 16, 64);
        pB += __shfl_xor(pB, 32, 64);

        h0 = psig(pA + biasA);
        h1 = psig(pB + biasB);

        // publish h for step t+1 into its ring slot (disjoint from DMA x-region)
        if (q == 0) {
            vbuf[(t + 1) & 3][j]      = h0;
            vbuf[(t + 1) & 3][16 + j] = h1;
        }
    }

    if (q == 0) {
        out[b * H_SZ + j]      = h0;
        out[b * H_SZ + 16 + j] = h1;
    }
}

// -----------------------------------------------------------------------------
extern "C" void kernel_launch(void* const* d_in, const int* in_sizes, int n_in,
                              void* d_out, int out_size, void* d_ws, size_t ws_size,
                              hipStream_t stream)
{
    const float* x    = (const float*)d_in[0];  // [256][4096][144]
    const float* W    = (const float*)d_in[1];  // [32][176]
    const float* bias = (const float*)d_in[2];  // [32]
    float* out = (float*)d_out;                 // [4096][32]
    (void)d_ws; (void)ws_size; (void)in_sizes; (void)n_in; (void)out_size;

    fused_rnn<<<B_SZ, 64, 0, stream>>>(x, W, bias, out);
}